// Round 2
// baseline (46.594 us; speedup 1.0000x reference)
//
#include <hip/hip_runtime.h>

#define NB 32
#define NT 128
#define NI 64
#define NH 512
#define HGB 32   // h per fused block
#define PSTR 45  // u64 stride per i in LDS pair table
typedef unsigned long long u64;
typedef unsigned int u32;
typedef unsigned char u8;

// ---- LDS layout (bytes) ----
// P    : 64*45*8  = 23040   byte-train pair table
// BUF  : 33280            phase A: xl[128][65] floats (33280)
//                         phase C: Wl2 (16384) + It[128][33] (16896)
// DL   : 16*32*4  = 2048    packed delays
// MM   : 64*2*8   = 1024    spike bitmasks
#define OFF_P 0
#define OFF_BUF 23040
#define OFF_WL2 23040
#define OFF_IT (23040 + 16384)
#define OFF_DL (23040 + 33280)
#define OFF_MM (OFF_DL + 2048)
#define SMEM_BYTES (OFF_MM + 1024)

// ---------------- K0: everything except the final h-reduction ----------------
// grid (b:32, hg:16); block 1024 = 16 waves. Lane = (hl:32, ch:2);
// c = wv*2+ch is the 4-t chunk (0..31). 32 waves/CU resident (2 blocks).
__global__ __launch_bounds__(1024, 8) void mega_kernel(
    const float* __restrict__ x, const float* __restrict__ w_ih,
    const float* __restrict__ draw, const float* __restrict__ w_read,
    float4* __restrict__ partial) {
  __shared__ char smem[SMEM_BYTES];
  u64* P = (u64*)(smem + OFF_P);
  float* xl = (float*)(smem + OFF_BUF);    // [NT][NI+1]
  float2* Wl2 = (float2*)(smem + OFF_WL2); // [NI*HGB] (w0,w1)
  float* It = (float*)(smem + OFF_IT);     // [NT][HGB+1]
  u32* Dlw = (u32*)(smem + OFF_DL);        // [(NI/4)*HGB]
  u64* Mm = (u64*)(smem + OFF_MM);         // [NI][2]

  const int tid = threadIdx.x;
  const int lane = tid & 63;
  const int wv = tid >> 6;                 // 0..15
  const int hl = lane & 31;
  const int ch = lane >> 5;
  const int c = wv * 2 + ch;               // t-chunk 0..31 (4 t each)
  const int b = blockIdx.x;
  const int hg = blockIdx.y;

  // ---- Phase A: stage x[b] -> xl[t][i] (coalesced float4 reads) ----
  {
    const float* xb = x + (size_t)b * (NT * NI);
    #pragma unroll
    for (int k2 = 0; k2 < 2; ++k2) {
      int e = (k2 * 1024 + tid) * 4;
      float4 v = *(const float4*)(xb + e);
      float* row = xl + (e >> 6) * (NI + 1) + (e & 63);
      row[0] = v.x; row[1] = v.y; row[2] = v.z; row[3] = v.w;
    }
  }
  __syncthreads();

  // ---- Phase A2: ballot-pack into per-i 128-bit masks ----
  #pragma unroll
  for (int j = 0; j < 8; ++j) {
    int idx = wv * 8 + j;  // 0..127 = i*2 + h2
    int i = idx >> 1;
    int h2 = idx & 1;
    u64 m = __ballot(xl[(h2 * 64 + lane) * (NI + 1) + i] != 0.0f);
    if (lane == 0) Mm[i * 2 + h2] = m;
  }
  __syncthreads();

  // ---- Phase B: masks -> zero-padded byte-train pair table ----
  // word w (0..45): bytes 4w..4w+3; byte 52+t = spike[t]; pads zero.
  for (int idx = tid; idx < NI * PSTR; idx += 1024) {
    int i = idx / PSTR;
    int k = idx - i * PSTR;
    u64 m0 = Mm[i * 2], m1 = Mm[i * 2 + 1];
    u32 lo = 0, hi = 0;
    if (k >= 13) {
      int t = (k - 13) * 4;
      u32 nib = (u32)(((t < 64) ? (m0 >> t) : (m1 >> (t - 64))) & 15);
      lo = (nib * 0x00204081u) & 0x01010101u;
    }
    if (k + 1 >= 13 && k + 1 < 45) {
      int t = (k - 12) * 4;
      u32 nib = (u32)(((t < 64) ? (m0 >> t) : (m1 >> (t - 64))) & 15);
      hi = (nib * 0x00204081u) & 0x01010101u;
    }
    P[idx] = ((u64)hi << 32) | lo;
  }

  // ---- Phase B2: per-synapse prep for this hg (paired weights + delays) ----
  if (tid < 512) {
    int i4 = tid & 15, hh = tid >> 4;  // hh = h-local 0..31
    int h = hg * HGB + hh;
    float4 wv4 = *((const float4*)(w_ih + (size_t)h * NI) + i4);
    float4 rv4 = *((const float4*)(draw + (size_t)h * NI) + i4);
    float wa[4] = {wv4.x, wv4.y, wv4.z, wv4.w};
    float ra[4] = {rv4.x, rv4.y, rv4.z, rv4.w};
    u32 dword = 0;
    #pragma unroll
    for (int jj = 0; jj < 4; ++jj) {
      float sig = 1.0f / (1.0f + expf(-ra[jj]));
      float d = sig * 50.0f;
      float d0f = floorf(d);
      float frac = d - d0f;
      int i0 = (int)d0f;
      float w0 = wa[jj] * (1.0f - frac);
      float w1 = wa[jj] * frac;
      if (i0 >= 50) { w0 += w1; w1 = 0.0f; i0 = 50; }  // safety fold
      int i = i4 * 4 + jj;
      Wl2[i * HGB + hh] = make_float2(w0, w1);
      dword |= (u32)i0 << (8 * jj);
    }
    Dlw[i4 * HGB + hh] = dword;
  }
  __syncthreads();

  // ---- Phase C: byte-window currents (4 t per thread) ----
  const int pbase = c * 4 + 50;
  float acc[4];
  #pragma unroll
  for (int j = 0; j < 4; ++j) acc[j] = 0.0f;

#define TAPS(IDX, W0, W1, D)                                   \
  do {                                                         \
    int p = pbase - (D);                                       \
    int k = p >> 2;                                            \
    int r8 = (p & 3) << 3;                                     \
    u64 A = P[(IDX) * PSTR + k];                               \
    u64 s1 = A >> r8;                                          \
    u32 a0 = (u32)s1, a1 = (u32)(s1 >> 32);                    \
    float f0 = (float)(a0 & 255u);                             \
    float f1 = (float)((a0 >> 8) & 255u);                      \
    float f2 = (float)((a0 >> 16) & 255u);                     \
    float f3 = (float)(a0 >> 24);                              \
    float f4 = (float)(a1 & 255u);                             \
    acc[0] += (W0) * f1 + (W1) * f0;                           \
    acc[1] += (W0) * f2 + (W1) * f1;                           \
    acc[2] += (W0) * f3 + (W1) * f2;                           \
    acc[3] += (W0) * f4 + (W1) * f3;                           \
  } while (0)

  #pragma unroll 4
  for (int i2 = 0; i2 < NI / 2; ++i2) {
    float2 qa = Wl2[(2 * i2) * HGB + hl];
    float2 qb = Wl2[(2 * i2 + 1) * HGB + hl];
    u32 dw = Dlw[(i2 >> 1) * HGB + hl];
    int sh = (i2 & 1) * 16;
    int d0 = (dw >> sh) & 255;
    int d1 = (dw >> (sh + 8)) & 255;
    TAPS(2 * i2, qa.x, qa.y, d0);
    TAPS(2 * i2 + 1, qb.x, qb.y, d1);
  }
#undef TAPS

  #pragma unroll
  for (int j = 0; j < 4; ++j) It[(c * 4 + j) * (HGB + 1) + hl] = acc[j];
  __syncthreads();

  // ---- Phase D: LIF scan (wave 0, 32 lanes) ----
  if (tid < HGB) {
    float v = 0.0f;
    int ref = 0;
    float c0 = 0.f, c1 = 0.f, c2 = 0.f, c3 = 0.f;
    #pragma unroll 8
    for (int t = 0; t < NT; ++t) {
      float I = It[t * (HGB + 1) + tid];
      bool act = (ref <= 0);
      float vn = act ? (v + 0.1f * (I - v)) : v;
      bool spk = act && (vn >= 1.0f);
      v = spk ? 0.0f : vn;
      ref = spk ? 2 : (ref > 0 ? ref - 1 : 0);
      if ((t & 31) >= 8) {
        float inc = spk ? 1.0f : 0.0f;
        if (t < 32) c0 += inc;
        else if (t < 64) c1 += inc;
        else if (t < 96) c2 += inc;
        else c3 += inc;
      }
    }
    int h = hg * HGB + tid;
    float wr = w_read[h];
    partial[b * NH + h] = make_float4(c0 * wr, c1 * wr, c2 * wr, c3 * wr);
  }
}

// ---------------- K1: deterministic reduce over h -> logits ----------------
__global__ __launch_bounds__(256) void reduce_kernel(
    const float* __restrict__ partial, const float* __restrict__ b_read,
    float* __restrict__ out) {
  int b = blockIdx.x >> 2;
  int k = blockIdx.x & 3;
  float s = 0.0f;
  for (int h = threadIdx.x; h < NH; h += 256)
    s += partial[(b * NH + h) * 4 + k];
  __shared__ float red[256];
  red[threadIdx.x] = s;
  __syncthreads();
  for (int off = 128; off > 0; off >>= 1) {
    if (threadIdx.x < off) red[threadIdx.x] += red[threadIdx.x + off];
    __syncthreads();
  }
  if (threadIdx.x == 0) out[blockIdx.x] = red[0] + b_read[0];
}

extern "C" void kernel_launch(void* const* d_in, const int* in_sizes, int n_in,
                              void* d_out, int out_size, void* d_ws, size_t ws_size,
                              hipStream_t stream) {
  const float* x      = (const float*)d_in[0];  // [B,T,NIN]
  const float* w_ih   = (const float*)d_in[1];  // [H,NIN]
  const float* draw   = (const float*)d_in[2];  // [H,NIN]
  const float* w_read = (const float*)d_in[3];  // [H]
  const float* b_read = (const float*)d_in[4];  // scalar

  float4* prt = (float4*)d_ws;  // 256 KB partials
  float*  out = (float*)d_out;

  mega_kernel<<<dim3(NB, NH / HGB), dim3(1024), 0, stream>>>(
      x, w_ih, draw, w_read, prt);
  reduce_kernel<<<dim3(NB * 4), dim3(256), 0, stream>>>(
      (const float*)prt, b_read, out);
}

// Round 3
// 45.199 us; speedup vs baseline: 1.0309x; 1.0309x over previous
//
#include <hip/hip_runtime.h>

#define NB 32
#define NT 128
#define NI 64
#define NH 512
#define HGB 32   // h per fused block
#define PSTR 45  // u64 stride per i in LDS pair table
typedef unsigned long long u64;
typedef unsigned int u32;
typedef unsigned char u8;

// ---- LDS layout (bytes) ----
// P    : 64*45*8  = 23040   byte-train pair table
// BUF  : 33280            phase A: xl[128][65] floats (33280)
//                         phase C: Wl4 (16384) + It[128][33] (16896)
// DL   : 16*32*4  = 2048    packed delays
// MM   : 64*2*8   = 1024    spike bitmasks
#define OFF_P 0
#define OFF_BUF 23040
#define OFF_WL 23040
#define OFF_IT (23040 + 16384)
#define OFF_DL (23040 + 33280)
#define OFF_MM (OFF_DL + 2048)
#define SMEM_BYTES (OFF_MM + 1024)

// ---------------- K0: everything except the final h-reduction ----------------
// grid (b:32, hg:16); block 1024 = 16 waves. Lane = (hl:32, ch:2);
// c = wv*2+ch is the 4-t chunk (0..31). 32 waves/CU resident (2 blocks).
__global__ __launch_bounds__(1024, 8) void mega_kernel(
    const float* __restrict__ x, const float* __restrict__ w_ih,
    const float* __restrict__ draw, const float* __restrict__ w_read,
    float4* __restrict__ partial) {
  __shared__ char smem[SMEM_BYTES];
  u64* P = (u64*)(smem + OFF_P);
  float* xl = (float*)(smem + OFF_BUF);     // [NT][NI+1]
  float4* Wl4 = (float4*)(smem + OFF_WL);   // [(NI/2)*HGB] (w0a,w1a,w0b,w1b)
  float* It = (float*)(smem + OFF_IT);      // [NT][HGB+1]
  u32* Dlw = (u32*)(smem + OFF_DL);         // [(NI/4)*HGB]
  u64* Mm = (u64*)(smem + OFF_MM);          // [NI][2]

  const int tid = threadIdx.x;
  const int lane = tid & 63;
  const int wv = tid >> 6;                 // 0..15
  const int hl = lane & 31;
  const int ch = lane >> 5;
  const int c = wv * 2 + ch;               // t-chunk 0..31 (4 t each)
  const int b = blockIdx.x;
  const int hg = blockIdx.y;

  // ---- Phase A: stage x[b] -> xl[t][i] (coalesced float4 reads) ----
  {
    const float* xb = x + (size_t)b * (NT * NI);
    #pragma unroll
    for (int k2 = 0; k2 < 2; ++k2) {
      int e = (k2 * 1024 + tid) * 4;
      float4 v = *(const float4*)(xb + e);
      float* row = xl + (e >> 6) * (NI + 1) + (e & 63);
      row[0] = v.x; row[1] = v.y; row[2] = v.z; row[3] = v.w;
    }
  }
  __syncthreads();

  // ---- Phase A2: ballot-pack into per-i 128-bit masks ----
  #pragma unroll
  for (int j = 0; j < 8; ++j) {
    int idx = wv * 8 + j;  // 0..127 = i*2 + h2
    int i = idx >> 1;
    int h2 = idx & 1;
    u64 m = __ballot(xl[(h2 * 64 + lane) * (NI + 1) + i] != 0.0f);
    if (lane == 0) Mm[i * 2 + h2] = m;
  }
  __syncthreads();

  // ---- Phase B: masks -> zero-padded byte-train pair table ----
  // word w (0..45): bytes 4w..4w+3; byte 52+t = spike[t]; pads zero.
  for (int idx = tid; idx < NI * PSTR; idx += 1024) {
    int i = idx / PSTR;
    int k = idx - i * PSTR;
    u64 m0 = Mm[i * 2], m1 = Mm[i * 2 + 1];
    u32 lo = 0, hi = 0;
    if (k >= 13) {
      int t = (k - 13) * 4;
      u32 nib = (u32)(((t < 64) ? (m0 >> t) : (m1 >> (t - 64))) & 15);
      lo = (nib * 0x00204081u) & 0x01010101u;
    }
    if (k + 1 >= 13 && k + 1 < 45) {
      int t = (k - 12) * 4;
      u32 nib = (u32)(((t < 64) ? (m0 >> t) : (m1 >> (t - 64))) & 15);
      hi = (nib * 0x00204081u) & 0x01010101u;
    }
    P[idx] = ((u64)hi << 32) | lo;
  }

  // ---- Phase B2: per-synapse prep for this hg (paired weights + delays) ----
  if (tid < 512) {
    int i4 = tid & 15, hh = tid >> 4;  // hh = h-local 0..31
    int h = hg * HGB + hh;
    float4 wv4 = *((const float4*)(w_ih + (size_t)h * NI) + i4);
    float4 rv4 = *((const float4*)(draw + (size_t)h * NI) + i4);
    float wa[4] = {wv4.x, wv4.y, wv4.z, wv4.w};
    float ra[4] = {rv4.x, rv4.y, rv4.z, rv4.w};
    float w0s[4], w1s[4];
    u32 dword = 0;
    #pragma unroll
    for (int jj = 0; jj < 4; ++jj) {
      float sig = 1.0f / (1.0f + expf(-ra[jj]));
      float d = sig * 50.0f;
      float d0f = floorf(d);
      float frac = d - d0f;
      int i0 = (int)d0f;
      float w0 = wa[jj] * (1.0f - frac);
      float w1 = wa[jj] * frac;
      if (i0 >= 50) { w0 += w1; w1 = 0.0f; i0 = 50; }  // safety fold
      w0s[jj] = w0; w1s[jj] = w1;
      dword |= (u32)i0 << (8 * jj);
    }
    Wl4[(2 * i4) * HGB + hh]     = make_float4(w0s[0], w1s[0], w0s[1], w1s[1]);
    Wl4[(2 * i4 + 1) * HGB + hh] = make_float4(w0s[2], w1s[2], w0s[3], w1s[3]);
    Dlw[i4 * HGB + hh] = dword;
  }
  __syncthreads();

  // ---- Phase C: byte-window currents (4 t per thread) ----
  const int pbase = c * 4 + 50;
  float acc[4];
  #pragma unroll
  for (int j = 0; j < 4; ++j) acc[j] = 0.0f;

  // Preload ALL packed delays into registers: kills the in-loop
  // dw -> addr -> A-load dependency chain so A-loads can pipeline.
  u32 dall[16];
  #pragma unroll
  for (int q = 0; q < 16; ++q) dall[q] = Dlw[q * HGB + hl];

#define TAPS(IDX, W0, W1, D)                                   \
  do {                                                         \
    int p = pbase - (D);                                       \
    int k = p >> 2;                                            \
    int r8 = (p & 3) << 3;                                     \
    u64 A = P[(IDX) * PSTR + k];                               \
    u64 s1 = A >> r8;                                          \
    u32 a0 = (u32)s1, a1 = (u32)(s1 >> 32);                    \
    float f0 = (float)(a0 & 255u);                             \
    float f1 = (float)((a0 >> 8) & 255u);                      \
    float f2 = (float)((a0 >> 16) & 255u);                     \
    float f3 = (float)(a0 >> 24);                              \
    float f4 = (float)(a1 & 255u);                             \
    acc[0] += (W0) * f1 + (W1) * f0;                           \
    acc[1] += (W0) * f2 + (W1) * f1;                           \
    acc[2] += (W0) * f3 + (W1) * f2;                           \
    acc[3] += (W0) * f4 + (W1) * f3;                           \
  } while (0)

  #pragma unroll
  for (int i4 = 0; i4 < 16; ++i4) {
    u32 dw = dall[i4];
    float4 wa = Wl4[(2 * i4) * HGB + hl];
    float4 wb = Wl4[(2 * i4 + 1) * HGB + hl];
    int d0 = dw & 255;
    int d1 = (dw >> 8) & 255;
    int d2 = (dw >> 16) & 255;
    int d3 = (dw >> 24) & 255;
    TAPS(4 * i4 + 0, wa.x, wa.y, d0);
    TAPS(4 * i4 + 1, wa.z, wa.w, d1);
    TAPS(4 * i4 + 2, wb.x, wb.y, d2);
    TAPS(4 * i4 + 3, wb.z, wb.w, d3);
  }
#undef TAPS

  #pragma unroll
  for (int j = 0; j < 4; ++j) It[(c * 4 + j) * (HGB + 1) + hl] = acc[j];
  __syncthreads();

  // ---- Phase D: LIF scan (wave 0, 32 lanes) ----
  if (tid < HGB) {
    float v = 0.0f;
    int ref = 0;
    float c0 = 0.f, c1 = 0.f, c2 = 0.f, c3 = 0.f;
    #pragma unroll 8
    for (int t = 0; t < NT; ++t) {
      float I = It[t * (HGB + 1) + tid];
      bool act = (ref <= 0);
      float vn = act ? (v + 0.1f * (I - v)) : v;
      bool spk = act && (vn >= 1.0f);
      v = spk ? 0.0f : vn;
      ref = spk ? 2 : (ref > 0 ? ref - 1 : 0);
      if ((t & 31) >= 8) {
        float inc = spk ? 1.0f : 0.0f;
        if (t < 32) c0 += inc;
        else if (t < 64) c1 += inc;
        else if (t < 96) c2 += inc;
        else c3 += inc;
      }
    }
    int h = hg * HGB + tid;
    float wr = w_read[h];
    partial[b * NH + h] = make_float4(c0 * wr, c1 * wr, c2 * wr, c3 * wr);
  }
}

// ---------------- K1: deterministic reduce over h -> logits ----------------
__global__ __launch_bounds__(256) void reduce_kernel(
    const float* __restrict__ partial, const float* __restrict__ b_read,
    float* __restrict__ out) {
  int b = blockIdx.x >> 2;
  int k = blockIdx.x & 3;
  float s = 0.0f;
  for (int h = threadIdx.x; h < NH; h += 256)
    s += partial[(b * NH + h) * 4 + k];
  __shared__ float red[256];
  red[threadIdx.x] = s;
  __syncthreads();
  for (int off = 128; off > 0; off >>= 1) {
    if (threadIdx.x < off) red[threadIdx.x] += red[threadIdx.x + off];
    __syncthreads();
  }
  if (threadIdx.x == 0) out[blockIdx.x] = red[0] + b_read[0];
}

extern "C" void kernel_launch(void* const* d_in, const int* in_sizes, int n_in,
                              void* d_out, int out_size, void* d_ws, size_t ws_size,
                              hipStream_t stream) {
  const float* x      = (const float*)d_in[0];  // [B,T,NIN]
  const float* w_ih   = (const float*)d_in[1];  // [H,NIN]
  const float* draw   = (const float*)d_in[2];  // [H,NIN]
  const float* w_read = (const float*)d_in[3];  // [H]
  const float* b_read = (const float*)d_in[4];  // scalar

  float4* prt = (float4*)d_ws;  // 256 KB partials
  float*  out = (float*)d_out;

  mega_kernel<<<dim3(NB, NH / HGB), dim3(1024), 0, stream>>>(
      x, w_ih, draw, w_read, prt);
  reduce_kernel<<<dim3(NB * 4), dim3(256), 0, stream>>>(
      (const float*)prt, b_read, out);
}

// Round 4
// 39.250 us; speedup vs baseline: 1.1871x; 1.1516x over previous
//
#include <hip/hip_runtime.h>

#define NB 32
#define NT 128
#define NI 64
#define NH 512
#define HGB 32   // h per cur block
#define PSTR 45  // u64 stride per i in LDS pair table
typedef unsigned long long u64;
typedef unsigned int u32;
typedef unsigned char u8;

// ---- LDS layout (bytes) ----
// P    : 64*45*8  = 23040   byte-train pair table
// BUF  : 33280             phase A: xl[128][65] floats; phase C: Wl4 (16 KB)
// DL   : 16*32*4  = 2048    packed delays
// MM   : 64*2*8   = 1024    spike bitmasks
#define OFF_P 0
#define OFF_BUF 23040
#define OFF_WL 23040
#define OFF_DL (23040 + 33280)
#define OFF_MM (OFF_DL + 2048)
#define SMEM_BYTES (OFF_MM + 1024)

// ---------------- K0: currents only (no LIF tail) ----------------
// grid (b:32, hg:16); block 1024 = 16 waves. Lane = (hl:32, ch:2);
// c = wv*2+ch is the 4-t chunk (0..31). 32 waves/CU resident (2 blocks).
// Ends with a global float4 store of acc -> I[b][h][t]; all waves exit
// together (the 27us single-wave LIF tail is moved to lif_kernel).
__global__ __launch_bounds__(1024, 8) void cur_kernel(
    const float* __restrict__ x, const float* __restrict__ w_ih,
    const float* __restrict__ draw, float4* __restrict__ Ig) {
  __shared__ char smem[SMEM_BYTES];
  u64* P = (u64*)(smem + OFF_P);
  float* xl = (float*)(smem + OFF_BUF);     // [NT][NI+1]
  float4* Wl4 = (float4*)(smem + OFF_WL);   // [(NI/2)*HGB] (w0a,w1a,w0b,w1b)
  u32* Dlw = (u32*)(smem + OFF_DL);         // [(NI/4)*HGB]
  u64* Mm = (u64*)(smem + OFF_MM);          // [NI][2]

  const int tid = threadIdx.x;
  const int lane = tid & 63;
  const int wv = tid >> 6;                 // 0..15
  const int hl = lane & 31;
  const int ch = lane >> 5;
  const int c = wv * 2 + ch;               // t-chunk 0..31 (4 t each)
  const int b = blockIdx.x;
  const int hg = blockIdx.y;

  // ---- Phase A: stage x[b] -> xl[t][i] (coalesced float4 reads) ----
  {
    const float* xb = x + (size_t)b * (NT * NI);
    #pragma unroll
    for (int k2 = 0; k2 < 2; ++k2) {
      int e = (k2 * 1024 + tid) * 4;
      float4 v = *(const float4*)(xb + e);
      float* row = xl + (e >> 6) * (NI + 1) + (e & 63);
      row[0] = v.x; row[1] = v.y; row[2] = v.z; row[3] = v.w;
    }
  }
  __syncthreads();

  // ---- Phase A2: ballot-pack into per-i 128-bit masks ----
  #pragma unroll
  for (int j = 0; j < 8; ++j) {
    int idx = wv * 8 + j;  // 0..127 = i*2 + h2
    int i = idx >> 1;
    int h2 = idx & 1;
    u64 m = __ballot(xl[(h2 * 64 + lane) * (NI + 1) + i] != 0.0f);
    if (lane == 0) Mm[i * 2 + h2] = m;
  }
  __syncthreads();

  // ---- Phase B: masks -> zero-padded byte-train pair table ----
  // word w (0..45): bytes 4w..4w+3; byte 52+t = spike[t]; pads zero.
  for (int idx = tid; idx < NI * PSTR; idx += 1024) {
    int i = idx / PSTR;
    int k = idx - i * PSTR;
    u64 m0 = Mm[i * 2], m1 = Mm[i * 2 + 1];
    u32 lo = 0, hi = 0;
    if (k >= 13) {
      int t = (k - 13) * 4;
      u32 nib = (u32)(((t < 64) ? (m0 >> t) : (m1 >> (t - 64))) & 15);
      lo = (nib * 0x00204081u) & 0x01010101u;
    }
    if (k + 1 >= 13 && k + 1 < 45) {
      int t = (k - 12) * 4;
      u32 nib = (u32)(((t < 64) ? (m0 >> t) : (m1 >> (t - 64))) & 15);
      hi = (nib * 0x00204081u) & 0x01010101u;
    }
    P[idx] = ((u64)hi << 32) | lo;
  }

  // ---- Phase B2: per-synapse prep for this hg (paired weights + delays) ----
  if (tid < 512) {
    int i4 = tid & 15, hh = tid >> 4;  // hh = h-local 0..31
    int h = hg * HGB + hh;
    float4 wv4 = *((const float4*)(w_ih + (size_t)h * NI) + i4);
    float4 rv4 = *((const float4*)(draw + (size_t)h * NI) + i4);
    float wa[4] = {wv4.x, wv4.y, wv4.z, wv4.w};
    float ra[4] = {rv4.x, rv4.y, rv4.z, rv4.w};
    float w0s[4], w1s[4];
    u32 dword = 0;
    #pragma unroll
    for (int jj = 0; jj < 4; ++jj) {
      float sig = 1.0f / (1.0f + expf(-ra[jj]));
      float d = sig * 50.0f;
      float d0f = floorf(d);
      float frac = d - d0f;
      int i0 = (int)d0f;
      float w0 = wa[jj] * (1.0f - frac);
      float w1 = wa[jj] * frac;
      if (i0 >= 50) { w0 += w1; w1 = 0.0f; i0 = 50; }  // safety fold
      w0s[jj] = w0; w1s[jj] = w1;
      dword |= (u32)i0 << (8 * jj);
    }
    Wl4[(2 * i4) * HGB + hh]     = make_float4(w0s[0], w1s[0], w0s[1], w1s[1]);
    Wl4[(2 * i4 + 1) * HGB + hh] = make_float4(w0s[2], w1s[2], w0s[3], w1s[3]);
    Dlw[i4 * HGB + hh] = dword;
  }
  __syncthreads();

  // ---- Phase C: byte-window currents (4 t per thread) ----
  const int pbase = c * 4 + 50;
  float acc[4];
  #pragma unroll
  for (int j = 0; j < 4; ++j) acc[j] = 0.0f;

  // Preload ALL packed delays into registers: kills the in-loop
  // dw -> addr -> A-load dependency chain so A-loads can pipeline.
  u32 dall[16];
  #pragma unroll
  for (int q = 0; q < 16; ++q) dall[q] = Dlw[q * HGB + hl];

#define TAPS(IDX, W0, W1, D)                                   \
  do {                                                         \
    int p = pbase - (D);                                       \
    int k = p >> 2;                                            \
    int r8 = (p & 3) << 3;                                     \
    u64 A = P[(IDX) * PSTR + k];                               \
    u64 s1 = A >> r8;                                          \
    u32 a0 = (u32)s1, a1 = (u32)(s1 >> 32);                    \
    float f0 = (float)(a0 & 255u);                             \
    float f1 = (float)((a0 >> 8) & 255u);                      \
    float f2 = (float)((a0 >> 16) & 255u);                     \
    float f3 = (float)(a0 >> 24);                              \
    float f4 = (float)(a1 & 255u);                             \
    acc[0] += (W0) * f1 + (W1) * f0;                           \
    acc[1] += (W0) * f2 + (W1) * f1;                           \
    acc[2] += (W0) * f3 + (W1) * f2;                           \
    acc[3] += (W0) * f4 + (W1) * f3;                           \
  } while (0)

  #pragma unroll
  for (int i4 = 0; i4 < 16; ++i4) {
    u32 dw = dall[i4];
    float4 wa = Wl4[(2 * i4) * HGB + hl];
    float4 wb = Wl4[(2 * i4 + 1) * HGB + hl];
    int d0 = dw & 255;
    int d1 = (dw >> 8) & 255;
    int d2 = (dw >> 16) & 255;
    int d3 = (dw >> 24) & 255;
    TAPS(4 * i4 + 0, wa.x, wa.y, d0);
    TAPS(4 * i4 + 1, wa.z, wa.w, d1);
    TAPS(4 * i4 + 2, wb.x, wb.y, d2);
    TAPS(4 * i4 + 3, wb.z, wb.w, d3);
  }
#undef TAPS

  // ---- store currents to global, t-contiguous: I[b][h][t] ----
  Ig[((size_t)b * NH + hg * HGB + hl) * (NT / 4) + c] =
      make_float4(acc[0], acc[1], acc[2], acc[3]);
}

// ---------------- K1: fully-parallel LIF scans ----------------
// 16384 independent (b,h) scans; 256 blocks x 64 threads = 1 wave/CU.
// 2-deep load pipeline; LIF math bit-identical to the fused version.
__global__ __launch_bounds__(64) void lif_kernel(
    const float4* __restrict__ Ig, const float* __restrict__ w_read,
    float4* __restrict__ partial) {
  const int g = blockIdx.x * 64 + threadIdx.x;  // g = b*NH + h
  const float4* row = Ig + (size_t)g * (NT / 4);

  float v = 0.0f;
  int ref = 0;
  float c0 = 0.f, c1 = 0.f, c2 = 0.f, c3 = 0.f;

  float4 cur = row[0];
  #pragma unroll
  for (int gq = 0; gq < NT / 4; ++gq) {
    float4 nxt = (gq < NT / 4 - 1) ? row[gq + 1] : make_float4(0.f, 0.f, 0.f, 0.f);
    float Iv[4] = {cur.x, cur.y, cur.z, cur.w};
    #pragma unroll
    for (int j = 0; j < 4; ++j) {
      const int t = gq * 4 + j;  // compile-time constant
      float I = Iv[j];
      bool act = (ref <= 0);
      float vn = act ? (v + 0.1f * (I - v)) : v;
      bool spk = act && (vn >= 1.0f);
      v = spk ? 0.0f : vn;
      ref = spk ? 2 : (ref > 0 ? ref - 1 : 0);
      if ((t & 31) >= 8) {
        float inc = spk ? 1.0f : 0.0f;
        if (t < 32) c0 += inc;
        else if (t < 64) c1 += inc;
        else if (t < 96) c2 += inc;
        else c3 += inc;
      }
    }
    cur = nxt;
  }
  float wr = w_read[g & (NH - 1)];
  partial[g] = make_float4(c0 * wr, c1 * wr, c2 * wr, c3 * wr);
}

// ---------------- K2: deterministic reduce over h -> logits ----------------
__global__ __launch_bounds__(256) void reduce_kernel(
    const float* __restrict__ partial, const float* __restrict__ b_read,
    float* __restrict__ out) {
  int b = blockIdx.x >> 2;
  int k = blockIdx.x & 3;
  float s = 0.0f;
  for (int h = threadIdx.x; h < NH; h += 256)
    s += partial[(b * NH + h) * 4 + k];
  __shared__ float red[256];
  red[threadIdx.x] = s;
  __syncthreads();
  for (int off = 128; off > 0; off >>= 1) {
    if (threadIdx.x < off) red[threadIdx.x] += red[threadIdx.x + off];
    __syncthreads();
  }
  if (threadIdx.x == 0) out[blockIdx.x] = red[0] + b_read[0];
}

extern "C" void kernel_launch(void* const* d_in, const int* in_sizes, int n_in,
                              void* d_out, int out_size, void* d_ws, size_t ws_size,
                              hipStream_t stream) {
  const float* x      = (const float*)d_in[0];  // [B,T,NIN]
  const float* w_ih   = (const float*)d_in[1];  // [H,NIN]
  const float* draw   = (const float*)d_in[2];  // [H,NIN]
  const float* w_read = (const float*)d_in[3];  // [H]
  const float* b_read = (const float*)d_in[4];  // scalar

  char* ws = (char*)d_ws;
  float4* Ig  = (float4*)ws;                        // 8 MB currents [b][h][t]
  float4* prt = (float4*)(ws + (16u << 20));        // 256 KB partials
  float*  out = (float*)d_out;

  cur_kernel<<<dim3(NB, NH / HGB), dim3(1024), 0, stream>>>(
      x, w_ih, draw, Ig);
  lif_kernel<<<dim3(NB * NH / 64), dim3(64), 0, stream>>>(
      Ig, w_read, prt);
  reduce_kernel<<<dim3(NB * 4), dim3(256), 0, stream>>>(
      (const float*)prt, b_read, out);
}